// Round 1
// baseline (353.853 us; speedup 1.0000x reference)
//
#include <hip/hip_runtime.h>

// Problem constants (UIGen_63058709840320): I=32000, L=2048, D=256.
// Key algebraic collapse: out = (weighted[L-2] + weighted[L-1]) @ D2, and the
// whole chain upstream only needs rows L-2, L-1 of posEmbed/dense1.
namespace {
constexpr int LL = 2048;
constexpr int II = 32000;
constexpr int DD = 256;

// ---- Kernel A: acc[0..255] = x[L-2] @ DE ; acc[256..511] = x[L-1] @ DE ----
// 250 blocks x 256 threads; each block covers 128 i's; lane = d-group (float4),
// sub = i interleave. Block-local LDS reduce, then 512 atomicAdds/block.
__global__ __launch_bounds__(256) void k_rows(const float* __restrict__ x,
                                              const float* __restrict__ DE,
                                              float* __restrict__ acc) {
  const int lane = threadIdx.x & 63;   // float4 group within D (64 * 4 = 256)
  const int sub  = threadIdx.x >> 6;   // 0..3, i interleave
  const float4* __restrict__ DE4 = reinterpret_cast<const float4*>(DE);
  const float* __restrict__ x0 = x + (size_t)(LL - 2) * II;
  const float* __restrict__ x1 = x + (size_t)(LL - 1) * II;
  const int i0 = blockIdx.x * 128;
  float4 a0 = {0.f, 0.f, 0.f, 0.f};
  float4 a1 = {0.f, 0.f, 0.f, 0.f};
#pragma unroll 8
  for (int ii = 0; ii < 32; ++ii) {
    const int i = i0 + sub + 4 * ii;
    const float4 de = DE4[(size_t)i * (DD / 4) + lane];
    const float s0 = x0[i];
    const float s1 = x1[i];
    a0.x = fmaf(s0, de.x, a0.x);
    a0.y = fmaf(s0, de.y, a0.y);
    a0.z = fmaf(s0, de.z, a0.z);
    a0.w = fmaf(s0, de.w, a0.w);
    a1.x = fmaf(s1, de.x, a1.x);
    a1.y = fmaf(s1, de.y, a1.y);
    a1.z = fmaf(s1, de.z, a1.z);
    a1.w = fmaf(s1, de.w, a1.w);
  }
  __shared__ float red[8][DD];  // [sub*2 + row][d]
  {
    float* r0 = &red[sub * 2 + 0][lane * 4];
    r0[0] = a0.x; r0[1] = a0.y; r0[2] = a0.z; r0[3] = a0.w;
    float* r1 = &red[sub * 2 + 1][lane * 4];
    r1[0] = a1.x; r1[1] = a1.y; r1[2] = a1.z; r1[3] = a1.w;
  }
  __syncthreads();
  const int d = threadIdx.x;
  atomicAdd(&acc[d],      red[0][d] + red[2][d] + red[4][d] + red[6][d]);
  atomicAdd(&acc[DD + d], red[1][d] + red[3][d] + red[5][d] + red[7][d]);
}

// ---- Kernel B1: dense1 rows L-2 (da) and L-1 (db) into dacc[0..511] ----
// dense1[d] = sum_k concat(posEmbed_row, pool1_row)[k] * D1[k][d].
// pool1 is ELEMENTWISE in d: pool1[L-2] = (a+b)/2047, pool1[L-1] = b/2048,
// so each k-chunk block rebuilds its slice of the concat vector locally.
__global__ __launch_bounds__(256) void k_dense1(const float* __restrict__ acc,
                                                const float* __restrict__ PE,
                                                const float* __restrict__ D1,
                                                float* __restrict__ dacc) {
  constexpr int KC = 32;
  __shared__ float va[KC], vb[KC];
  const int k0 = blockIdx.x * KC;
  const int t = threadIdx.x;
  if (t < KC) {
    const int k = k0 + t;
    const int j = (k < DD) ? k : (k - DD);
    const float a = acc[j]      + PE[(size_t)(LL - 2) * DD + j];
    const float b = acc[DD + j] + PE[(size_t)(LL - 1) * DD + j];
    if (k < DD) {
      va[t] = a;
      vb[t] = b;
    } else {
      va[t] = (a + b) * (1.0f / (float)(LL - 1));
      vb[t] = b * (1.0f / (float)LL);
    }
  }
  __syncthreads();
  float sa = 0.f, sb = 0.f;
#pragma unroll 8
  for (int kk = 0; kk < KC; ++kk) {
    const float w = D1[(size_t)(k0 + kk) * DD + t];
    sa = fmaf(va[kk], w, sa);
    sb = fmaf(vb[kk], w, sb);
  }
  atomicAdd(&dacc[t], sa);
  atomicAdd(&dacc[DD + t], sb);
}

// ---- Kernel B2: attention rows L-2/L-1 into aacc[0..511] (same trick) ----
__global__ __launch_bounds__(256) void k_att(const float* __restrict__ dacc,
                                             const float* __restrict__ Att,
                                             float* __restrict__ aacc) {
  constexpr int KC = 32;
  __shared__ float wa[KC], wb[KC];
  const int k0 = blockIdx.x * KC;
  const int t = threadIdx.x;
  if (t < KC) {
    const int k = k0 + t;
    const int j = (k < DD) ? k : (k - DD);
    const float da = dacc[j];
    const float db = dacc[DD + j];
    if (k < DD) {
      wa[t] = da;
      wb[t] = db;
    } else {
      wa[t] = (da + db) * (1.0f / (float)(LL - 1));
      wb[t] = db * (1.0f / (float)LL);
    }
  }
  __syncthreads();
  float ta = 0.f, tb = 0.f;
#pragma unroll 8
  for (int kk = 0; kk < KC; ++kk) {
    const float w = Att[(size_t)(k0 + kk) * DD + t];
    ta = fmaf(wa[kk], w, ta);
    tb = fmaf(wb[kk], w, tb);
  }
  atomicAdd(&aacc[t], ta);
  atomicAdd(&aacc[DD + t], tb);
}

// ---- Kernel C: out[i] = sum_d s[d] * D2[d][i],
//      s[d] = da[d]*ta[d] + db[d]*tb[d]  (weighted[L-2]+weighted[L-1]) ----
// Grid (32, 8): x = float4 i-chunks, y = 32-wide d-chunks (split-K atomics).
__global__ __launch_bounds__(256) void k_out(const float* __restrict__ dacc,
                                             const float* __restrict__ aacc,
                                             const float* __restrict__ D2,
                                             float* __restrict__ out) {
  __shared__ float sv[32];
  const int dbase = blockIdx.y * 32;
  if (threadIdx.x < 32) {
    const int dd = dbase + threadIdx.x;
    const float da = dacc[dd], db = dacc[DD + dd];
    const float ta = aacc[dd], tb = aacc[DD + dd];
    sv[threadIdx.x] = fmaf(da, ta, db * tb);
  }
  __syncthreads();
  const int i4 = blockIdx.x * 256 + threadIdx.x;  // float4 index, II/4 = 8000
  if (i4 < II / 4) {
    const float4* __restrict__ D24 = reinterpret_cast<const float4*>(D2);
    float4 a = {0.f, 0.f, 0.f, 0.f};
#pragma unroll 8
    for (int k = 0; k < 32; ++k) {
      const float4 v = D24[(size_t)(dbase + k) * (II / 4) + i4];
      const float sk = sv[k];
      a.x = fmaf(sk, v.x, a.x);
      a.y = fmaf(sk, v.y, a.y);
      a.z = fmaf(sk, v.z, a.z);
      a.w = fmaf(sk, v.w, a.w);
    }
    float* o = out + 4 * (size_t)i4;
    atomicAdd(&o[0], a.x);
    atomicAdd(&o[1], a.y);
    atomicAdd(&o[2], a.z);
    atomicAdd(&o[3], a.w);
  }
}

}  // namespace

extern "C" void kernel_launch(void* const* d_in, const int* in_sizes, int n_in,
                              void* d_out, int out_size, void* d_ws, size_t ws_size,
                              hipStream_t stream) {
  (void)in_sizes; (void)n_in; (void)ws_size;
  const float* x   = (const float*)d_in[0];  // [L, I]
  const float* DE  = (const float*)d_in[1];  // [I, D]
  const float* PE  = (const float*)d_in[2];  // [L, D]
  const float* D1  = (const float*)d_in[3];  // [2D, D]
  const float* D2  = (const float*)d_in[4];  // [D, I]
  const float* Att = (const float*)d_in[5];  // [2D, D]
  float* out = (float*)d_out;                // [1, I] fp32
  float* ws = (float*)d_ws;

  float* acc  = ws;          // [2*D]  posEmbed rows L-2, L-1 (pre-PE)
  float* dacc = ws + 512;    // [2*D]  dense1 rows
  float* aacc = ws + 1024;   // [2*D]  attention rows

  // ws and out are poisoned 0xAA before every launch — zero the accumulators.
  hipMemsetAsync(ws, 0, 1536 * sizeof(float), stream);
  hipMemsetAsync(d_out, 0, (size_t)out_size * sizeof(float), stream);

  k_rows<<<II / 128, 256, 0, stream>>>(x, DE, acc);            // 250 blocks
  k_dense1<<<(2 * DD) / 32, 256, 0, stream>>>(acc, PE, D1, dacc);  // 16 blocks
  k_att<<<(2 * DD) / 32, 256, 0, stream>>>(dacc, Att, aacc);       // 16 blocks
  k_out<<<dim3((II / 4 + 255) / 256, 8), 256, 0, stream>>>(dacc, aacc, D2, out);
}